// Round 6
// baseline (243.601 us; speedup 1.0000x reference)
//
#include <hip/hip_runtime.h>
#include <stdint.h>

typedef __attribute__((ext_vector_type(8))) short short8;
typedef __attribute__((ext_vector_type(4))) short short4v;
typedef __attribute__((ext_vector_type(4))) float float4v;

#define MFMA16(a, b, c) __builtin_amdgcn_mfma_f32_16x16x32_bf16((a), (b), (c), 0, 0, 0)

__device__ __forceinline__ ushort f2bf_rne(float f) {
  union { float f; unsigned u; } x; x.f = f;
  unsigned r = x.u + 0x7FFFu + ((x.u >> 16) & 1u);
  return (ushort)(r >> 16);
}
__device__ __forceinline__ ushort f2bf_trunc(float f) {
  union { float f; unsigned u; } x; x.f = f;
  return (ushort)(x.u >> 16);
}
__device__ __forceinline__ void gload16(const ushort* g, ushort* lds) {
  __builtin_amdgcn_global_load_lds(
      (__attribute__((address_space(1))) unsigned int*)g,
      (__attribute__((address_space(3))) unsigned int*)lds, 16, 0, 0);
}

// scale*log2(e): baked into Qh so attention uses raw exp2 on scores.
#define CEXP 0.1803368801111204f

// ---------------------------------------------------------------------------
// 64x64 transpose (f32 in, bf16 out): out[c*os + r] = bf16(in[r*is + c])
// ---------------------------------------------------------------------------
__device__ __forceinline__ void transpose64f(const float* __restrict__ in, int is,
                                             ushort* __restrict__ out, int os,
                                             ushort* lds /*64*72*/) {
  const int t = threadIdx.x;
#pragma unroll
  for (int it = 0; it < 2; ++it) {
    int e = it * 2048 + t * 8;
    int r = e >> 6, c = e & 63;
    const float* p = in + (size_t)r * is + c;
    float4 x0 = *(const float4*)p;
    float4 x1 = *(const float4*)(p + 4);
    ushort tv[8] __attribute__((aligned(16))) = {
        f2bf_rne(x0.x), f2bf_rne(x0.y), f2bf_rne(x0.z), f2bf_rne(x0.w),
        f2bf_rne(x1.x), f2bf_rne(x1.y), f2bf_rne(x1.z), f2bf_rne(x1.w)};
    *(uint4*)&lds[r * 72 + c] = *(const uint4*)tv;
  }
  __syncthreads();
  const int cc = t >> 2;
  const int rg = (t & 3) * 16;
  ushort tmp[16] __attribute__((aligned(16)));
#pragma unroll
  for (int i = 0; i < 16; ++i) tmp[i] = lds[(rg + i) * 72 + cc];
  *(uint4*)&out[(size_t)cc * os + rg] = *(const uint4*)&tmp[0];
  *(uint4*)&out[(size_t)cc * os + rg + 8] = *(const uint4*)&tmp[8];
}

// ---------------------------------------------------------------------------
// prep: f32->bf16 convert of Q,K,V (4M each) + Wo (1M), and Wq/Wk/Wv repack.
// grid.x = 6144 (QKV) + 512 (Wo) + 768 (repack) = 7424
// ---------------------------------------------------------------------------
__global__ __launch_bounds__(256) void prep_kernel(
    const float* __restrict__ Q, const float* __restrict__ K,
    const float* __restrict__ V, const float* __restrict__ Wo,
    const float* __restrict__ Wq, const float* __restrict__ Wk,
    const float* __restrict__ Wv, ushort* __restrict__ Qb, ushort* __restrict__ Kb,
    ushort* __restrict__ Vb, ushort* __restrict__ WoB, ushort* __restrict__ BtQ,
    ushort* __restrict__ BtK, ushort* __restrict__ BtV) {
  __shared__ ushort lds[64 * 72];
  const int bx = blockIdx.x;
  if (bx < 6656) {
    const float* s;
    ushort* d;
    int i;
    if (bx < 6144) {
      const int plane = bx >> 11;
      s = plane == 0 ? Q : (plane == 1 ? K : V);
      d = plane == 0 ? Qb : (plane == 1 ? Kb : Vb);
      i = ((bx & 2047) * 256 + threadIdx.x) * 8;
    } else {
      s = Wo;
      d = WoB;
      i = ((bx - 6144) * 256 + threadIdx.x) * 8;
    }
    float4 a = *(const float4*)(s + i);
    float4 b = *(const float4*)(s + i + 4);
    ushort t[8] __attribute__((aligned(16))) = {
        f2bf_rne(a.x), f2bf_rne(a.y), f2bf_rne(a.z), f2bf_rne(a.w),
        f2bf_rne(b.x), f2bf_rne(b.y), f2bf_rne(b.z), f2bf_rne(b.w)};
    *(uint4*)(d + i) = *(const uint4*)t;
  } else {
    const int rb = bx - 6656;
    const int dt = rb & 15, h = (rb >> 4) & 15, z = rb >> 8;
    const float* W = z == 0 ? Wq : (z == 1 ? Wk : Wv);
    ushort* Bt = z == 0 ? BtQ : (z == 1 ? BtK : BtV);
    transpose64f(W + h * 65536 + dt * 4096, 64, Bt + h * 65536 + dt * 64, 1024, lds);
  }
}

// standalone repack for the fallback path
__global__ __launch_bounds__(256, 2) void repack_w_kernel(
    const float* __restrict__ Wq, const float* __restrict__ Wk,
    const float* __restrict__ Wv, ushort* __restrict__ BtQ, ushort* __restrict__ BtK,
    ushort* __restrict__ BtV) {
  __shared__ ushort lds[64 * 72];
  const float* W = blockIdx.z == 0 ? Wq : (blockIdx.z == 1 ? Wk : Wv);
  ushort* Bt = blockIdx.z == 0 ? BtQ : (blockIdx.z == 1 ? BtK : BtV);
  const int h = blockIdx.y, dt = blockIdx.x;
  transpose64f(W + h * 65536 + dt * 4096, 64, Bt + h * 65536 + dt * 64, 1024, lds);
}

// ---------------------------------------------------------------------------
// Pipelined GEMM: C = (A[M,K] @ Bt[N,K]^T + bias)*ascale, all-bf16 operands.
// Double-buffered LDS; per step: issue 4 DMAs for next buffer, wait
// vmcnt(4) (prev buffer's DMAs done, next's stay in flight), raw s_barrier,
// compute, lgkmcnt(0)+s_barrier (WAR). Never drains the DMA queue to 0.
// cmode: 0 bf16 row-major, 1 bf16 coalesced transpose into Vt[b,h,dk,t],
//        2 f32 row-major. lA/lB are 2*4096 u16 each.
// ---------------------------------------------------------------------------
__device__ __forceinline__ void gemm_pipe(const ushort* __restrict__ A,
                                          const ushort* __restrict__ Bt,
                                          const float* __restrict__ bias,
                                          void* __restrict__ C, int cmode, float ascale,
                                          int N, int K, ushort* lA, ushort* lB) {
  const int tid = threadIdx.x;
  const int l = tid & 63, lane15 = l & 15, quad = l >> 4;
  const int mbase = blockIdx.y * 128, nbase = blockIdx.x * 128;
  const int wv = tid >> 6;
  const int wrow = (wv >> 1) * 64, wcol = (wv & 1) * 64;

  const int e0 = tid * 8;
  const int e1 = 2048 + tid * 8;
  const int r0 = e0 >> 5, c0 = e0 & 31;
  const int r1 = e1 >> 5, c1 = e1 & 31;
  const ushort* Ag0 = A + (size_t)(mbase + r0) * K + c0;
  const ushort* Ag1 = A + (size_t)(mbase + r1) * K + c1;
  const ushort* Bg0 = Bt + (size_t)(nbase + r0) * K + c0;
  const ushort* Bg1 = Bt + (size_t)(nbase + r1) * K + c1;

  float4v acc[4][4];
#pragma unroll
  for (int i = 0; i < 4; ++i)
#pragma unroll
    for (int j = 0; j < 4; ++j) acc[i][j] = (float4v){0.f, 0.f, 0.f, 0.f};

  // prologue: stage buffer 0
  gload16(Ag0, lA + e0);
  gload16(Ag1, lA + e1);
  gload16(Bg0, lB + e0);
  gload16(Bg1, lB + e1);

  for (int kb = 0; kb < K; kb += 32) {
    const int p = (kb >> 5) & 1;
    const int kn = (kb + 32 < K) ? kb + 32 : 0;  // last iter re-stages 0 (unread)
    const int q = (p ^ 1) * 4096;
    gload16(Ag0 + kn, lA + q + e0);
    gload16(Ag1 + kn, lA + q + e1);
    gload16(Bg0 + kn, lB + q + e0);
    gload16(Bg1 + kn, lB + q + e1);
    asm volatile("s_waitcnt vmcnt(4)\ns_barrier" ::: "memory");
    const int base = p * 4096;
    short8 a[4], b[4];
#pragma unroll
    for (int i = 0; i < 4; ++i) {
      a[i] = *(const short8*)&lA[base + (wrow + i * 16 + lane15) * 32 + quad * 8];
      b[i] = *(const short8*)&lB[base + (wcol + i * 16 + lane15) * 32 + quad * 8];
    }
#pragma unroll
    for (int i = 0; i < 4; ++i)
#pragma unroll
      for (int j = 0; j < 4; ++j) acc[i][j] = MFMA16(a[i], b[j], acc[i][j]);
    asm volatile("s_waitcnt lgkmcnt(0)\ns_barrier" ::: "memory");
  }

  if (cmode == 1) {
    // coalesced transposed epilogue into Vt[b,h,dk,t]:
    // wave transposes each 64(m)x16(n) frag-column group through LDS, then
    // writes 16B-contiguous t-segments of Vt rows.
    asm volatile("s_waitcnt vmcnt(0) lgkmcnt(0)\ns_barrier" ::: "memory");
    uint* sp = (uint*)lA + wv * 576;  // 2304 B per wave, lA = 16 KB total
    const int bb = mbase >> 11;
    const int tb = (mbase & 2047) + wrow;
#pragma unroll
    for (int j = 0; j < 4; ++j) {
      {
        const int n = nbase + wcol + j * 16 + lane15;
        const float bvs = bias[n];
#pragma unroll
        for (int i = 0; i < 4; ++i)
#pragma unroll
          for (int rp = 0; rp < 2; ++rp) {
            const uint lo = f2bf_rne((acc[i][j][2 * rp] + bvs) * ascale);
            const uint hi = f2bf_rne((acc[i][j][2 * rp + 1] + bvs) * ascale);
            sp[36 * lane15 + i * 8 + quad * 2 + rp] = lo | (hi << 16);
          }
      }
#pragma unroll
      for (int t = 0; t < 2; ++t) {
        const int row = t * 8 + (l >> 3);  // n_local
        const int c = l & 7;               // m chunk (8 consecutive m)
        uint4 d = *(const uint4*)(sp + 36 * row + 4 * c);
        const int ng = nbase + wcol + j * 16 + row;
        ushort* dst = (ushort*)C + ((size_t)(bb * 1024 + ng)) * 2048 + tb + c * 8;
        *(uint4*)dst = d;
      }
    }
    return;
  }

#pragma unroll
  for (int j = 0; j < 4; ++j) {
    const int n = nbase + wcol + j * 16 + lane15;
    const float bvs = bias[n];
#pragma unroll
    for (int i = 0; i < 4; ++i) {
      const int m0 = mbase + wrow + i * 16 + quad * 4;
#pragma unroll
      for (int r = 0; r < 4; ++r) {
        const float val = (acc[i][j][r] + bvs) * ascale;
        if (cmode == 2)
          ((float*)C)[(size_t)(m0 + r) * N + n] = val;
        else
          ((ushort*)C)[(size_t)(m0 + r) * N + n] = f2bf_rne(val);
      }
    }
  }
}

__global__ __launch_bounds__(256, 2) void proj3_kernel(
    const ushort* __restrict__ Qb, const ushort* __restrict__ Kb,
    const ushort* __restrict__ Vb, const ushort* __restrict__ BtQ,
    const ushort* __restrict__ BtK, const ushort* __restrict__ BtV,
    const float* __restrict__ bq, const float* __restrict__ bk,
    const float* __restrict__ bv, ushort* __restrict__ Qh, ushort* __restrict__ Kh,
    ushort* __restrict__ Vt) {
  __shared__ ushort lA[2 * 4096], lB[2 * 4096];
  const ushort *Aop, *Bop;
  const float* bs;
  ushort* Cp;
  int cm;
  float as;
  if (blockIdx.z == 0) { Aop = Qb; Bop = BtQ; bs = bq; Cp = Qh; cm = 0; as = CEXP; }
  else if (blockIdx.z == 1) { Aop = Kb; Bop = BtK; bs = bk; Cp = Kh; cm = 0; as = 1.0f; }
  else { Aop = Vb; Bop = BtV; bs = bv; Cp = Vt; cm = 1; as = 1.0f; }
  gemm_pipe(Aop, Bop, bs, Cp, cm, as, 1024, 1024, lA, lB);
}

__global__ __launch_bounds__(256, 2) void gemm_bt_kernel(
    const ushort* __restrict__ X, const ushort* __restrict__ WoB,
    const float* __restrict__ bo, float* __restrict__ out) {
  __shared__ ushort lA[2 * 4096], lB[2 * 4096];
  gemm_pipe(X, WoB, bo, out, 2, 1.0f, 1024, 1024, lA, lB);
}

// ---------------------------------------------------------------------------
// fallback-path GEMM (f32 operands allowed), round-5 structure (known-good)
// ---------------------------------------------------------------------------
template <int F32>
__device__ __forceinline__ void stage16(const void* G, size_t eoff, ushort* ldst) {
  if (F32) {
    const float* p = (const float*)G + eoff;
    float4 x0 = *(const float4*)p;
    float4 x1 = *(const float4*)(p + 4);
    ushort t[8] __attribute__((aligned(16))) = {
        f2bf_rne(x0.x), f2bf_rne(x0.y), f2bf_rne(x0.z), f2bf_rne(x0.w),
        f2bf_rne(x1.x), f2bf_rne(x1.y), f2bf_rne(x1.z), f2bf_rne(x1.w)};
    *(uint4*)ldst = *(const uint4*)t;
  } else {
    gload16((const ushort*)G + eoff, ldst);
  }
}

template <int AF32, int BF32>
__device__ __forceinline__ void gemm_body_basic(const void* __restrict__ A,
                                                const void* __restrict__ Bt,
                                                const float* __restrict__ bias,
                                                void* __restrict__ C, int cmode,
                                                float ascale, int N, int K, ushort* lA,
                                                ushort* lB) {
  const int tid = threadIdx.x;
  const int l = tid & 63, lane15 = l & 15, quad = l >> 4;
  const int mbase = blockIdx.y * 128, nbase = blockIdx.x * 128;
  const int w = tid >> 6;
  const int wrow = (w >> 1) * 64, wcol = (w & 1) * 64;
  const int e0 = tid * 8;
  const int e1 = 2048 + tid * 8;
  const int r0 = e0 >> 5, c0 = e0 & 31;
  const int r1 = e1 >> 5, c1 = e1 & 31;

  float4v acc[4][4];
#pragma unroll
  for (int i = 0; i < 4; ++i)
#pragma unroll
    for (int j = 0; j < 4; ++j) acc[i][j] = (float4v){0.f, 0.f, 0.f, 0.f};

  for (int kb = 0; kb < K; kb += 32) {
    __syncthreads();
    stage16<AF32>(A, (size_t)(mbase + r0) * K + c0 + kb, &lA[e0]);
    stage16<AF32>(A, (size_t)(mbase + r1) * K + c1 + kb, &lA[e1]);
    stage16<BF32>(Bt, (size_t)(nbase + r0) * K + c0 + kb, &lB[e0]);
    stage16<BF32>(Bt, (size_t)(nbase + r1) * K + c1 + kb, &lB[e1]);
    asm volatile("s_waitcnt vmcnt(0)" ::: "memory");
    __syncthreads();
    short8 a[4], b[4];
#pragma unroll
    for (int i = 0; i < 4; ++i) {
      a[i] = *(const short8*)&lA[(wrow + i * 16 + lane15) * 32 + quad * 8];
      b[i] = *(const short8*)&lB[(wcol + i * 16 + lane15) * 32 + quad * 8];
    }
#pragma unroll
    for (int i = 0; i < 4; ++i)
#pragma unroll
      for (int j = 0; j < 4; ++j) acc[i][j] = MFMA16(a[i], b[j], acc[i][j]);
  }

#pragma unroll
  for (int j = 0; j < 4; ++j) {
    const int n = nbase + wcol + j * 16 + lane15;
    const float bvs = bias[n];
#pragma unroll
    for (int i = 0; i < 4; ++i) {
      const int m0 = mbase + wrow + i * 16 + quad * 4;
#pragma unroll
      for (int r = 0; r < 4; ++r) {
        const float val = (acc[i][j][r] + bvs) * ascale;
        if (cmode == 1) {
          const int m = m0 + r;
          const int bb = m >> 11, t = m & 2047;
          ((ushort*)C)[((size_t)(bb * 1024 + n)) * 2048 + t] = f2bf_rne(val);
        } else if (cmode == 2) {
          ((float*)C)[(size_t)(m0 + r) * N + n] = val;
        } else {
          ((ushort*)C)[(size_t)(m0 + r) * N + n] = f2bf_rne(val);
        }
      }
    }
  }
}

__global__ __launch_bounds__(256, 2) void proj3f_kernel(
    const float* __restrict__ Q, const float* __restrict__ Kin,
    const float* __restrict__ V, const ushort* __restrict__ BtQ,
    const ushort* __restrict__ BtK, const ushort* __restrict__ BtV,
    const float* __restrict__ bq, const float* __restrict__ bk,
    const float* __restrict__ bv, ushort* __restrict__ Qh, ushort* __restrict__ Kh,
    ushort* __restrict__ Vt) {
  __shared__ ushort lA[128 * 32], lB[128 * 32];
  if (blockIdx.z == 0)
    gemm_body_basic<1, 0>(Q, BtQ, bq, Qh, 0, CEXP, 1024, 1024, lA, lB);
  else if (blockIdx.z == 1)
    gemm_body_basic<1, 0>(Kin, BtK, bk, Kh, 0, 1.0f, 1024, 1024, lA, lB);
  else
    gemm_body_basic<1, 0>(V, BtV, bv, Vt, 1, 1.0f, 1024, 1024, lA, lB);
}

__global__ __launch_bounds__(256, 2) void gemm_btf_kernel(
    const ushort* __restrict__ X, const float* __restrict__ Wo,
    const float* __restrict__ bo, float* __restrict__ out) {
  __shared__ ushort lA[128 * 32], lB[128 * 32];
  gemm_body_basic<0, 1>(X, Wo, bo, out, 2, 1.0f, 1024, 1024, lA, lB);
}

// ---------------------------------------------------------------------------
// Flash attention v3: same geometry as v2 (grid (bh=32, qtile=32), XCD-local
// K/V, swizzled LDS tiles) + double-buffered pipelined staging.
// ---------------------------------------------------------------------------
__global__ __launch_bounds__(256, 3) void attn_kernel(const ushort* __restrict__ Qh,
                                                      const ushort* __restrict__ Kh,
                                                      const ushort* __restrict__ Vt,
                                                      ushort* __restrict__ ctxout) {
  __shared__ ushort lK[2 * 4096];  // [buf][key][dkblk^..] swizzled
  __shared__ ushort lV[2 * 4096];  // [buf][dk][keyblk^..] swizzled
  __shared__ ushort pl_all[4][16 * 68];
  const int tid = threadIdx.x, l = tid & 63, wv = tid >> 6;
  const int lane15 = l & 15, quad = l >> 4;
  const int bh = blockIdx.x, b = bh >> 4, h = bh & 15;
  const int q0 = blockIdx.y * 64 + wv * 16;

  const int sr = tid >> 3;
  const int scb = (tid & 7) ^ (sr & 7);
  const ushort* Kp = Kh + (size_t)(b * 2048) * 1024 + h * 64;
  const ushort* Vp = Vt + (size_t)(bh * 64) * 2048;
  const ushort* Kg0 = Kp + (size_t)sr * 1024 + scb * 8;
  const ushort* Kg1 = Kg0 + 32 * 1024;
  const ushort* Vg0 = Vp + (size_t)sr * 2048 + scb * 8;
  const ushort* Vg1 = Vg0 + 32 * 2048;

  const ushort* qrow = Qh + (size_t)(b * 2048 + q0 + lane15) * 1024 + h * 64;
  const short8 qa0 = *(const short8*)&qrow[quad * 8];
  const short8 qa1 = *(const short8*)&qrow[32 + quad * 8];

  const int xm = lane15 & 7;
  const int fr0 = lane15 * 64 + ((quad ^ xm) * 8);
  const int fr1 = lane15 * 64 + (((quad + 4) ^ xm) * 8);

  ushort* pl = &pl_all[wv][0];
  const short8 ones = {0x3F80, 0x3F80, 0x3F80, 0x3F80, 0x3F80, 0x3F80, 0x3F80, 0x3F80};

  float4v o[4];
  float4v lf = (float4v){0.f, 0.f, 0.f, 0.f};
#pragma unroll
  for (int i = 0; i < 4; ++i) o[i] = (float4v){0.f, 0.f, 0.f, 0.f};

  // prologue: stage buffer 0 (s=0)
  gload16(Kg0, lK + tid * 8);
  gload16(Kg1, lK + 2048 + tid * 8);
  gload16(Vg0, lV + tid * 8);
  gload16(Vg1, lV + 2048 + tid * 8);

  for (int s0 = 0; s0 < 2048; s0 += 64) {
    const int p = (s0 >> 6) & 1;
    const int sn = (s0 + 64 < 2048) ? s0 + 64 : 0;  // last iter: dummy restage
    const int q = (p ^ 1) * 4096;
    gload16(Kg0 + (size_t)sn * 1024, lK + q + tid * 8);
    gload16(Kg1 + (size_t)sn * 1024, lK + q + 2048 + tid * 8);
    gload16(Vg0 + sn, lV + q + tid * 8);
    gload16(Vg1 + sn, lV + q + 2048 + tid * 8);
    asm volatile("s_waitcnt vmcnt(4)\ns_barrier" ::: "memory");
    const int base = p * 4096;

    // S2 = (Q*CEXP) K^T
    float4v sb[4];
#pragma unroll
    for (int i = 0; i < 4; ++i) {
      short8 k0 = *(const short8*)&lK[base + i * 1024 + fr0];
      short8 k1 = *(const short8*)&lK[base + i * 1024 + fr1];
      float4v c = (float4v){0.f, 0.f, 0.f, 0.f};
      c = MFMA16(qa0, k0, c);
      c = MFMA16(qa1, k1, c);
      sb[i] = c;
    }
    // P = exp2(S2): C-layout -> wave-private LDS -> A-layout
#pragma unroll
    for (int i = 0; i < 4; ++i)
#pragma unroll
      for (int r = 0; r < 4; ++r)
        pl[(quad * 4 + r) * 68 + i * 16 + lane15] =
            f2bf_trunc(__builtin_amdgcn_exp2f(sb[i][r]));
    short4v p0a = *(const short4v*)&pl[lane15 * 68 + quad * 8];
    short4v p0b = *(const short4v*)&pl[lane15 * 68 + quad * 8 + 4];
    short4v p1a = *(const short4v*)&pl[lane15 * 68 + 32 + quad * 8];
    short4v p1b = *(const short4v*)&pl[lane15 * 68 + 32 + quad * 8 + 4];
    short8 pa0 = __builtin_shufflevector(p0a, p0b, 0, 1, 2, 3, 4, 5, 6, 7);
    short8 pa1 = __builtin_shufflevector(p1a, p1b, 0, 1, 2, 3, 4, 5, 6, 7);
    // l += rowsum(P); O += P V
    lf = MFMA16(pa0, ones, lf);
    lf = MFMA16(pa1, ones, lf);
#pragma unroll
    for (int nf = 0; nf < 4; ++nf) {
      short8 v0 = *(const short8*)&lV[base + nf * 1024 + fr0];
      short8 v1 = *(const short8*)&lV[base + nf * 1024 + fr1];
      o[nf] = MFMA16(pa0, v0, o[nf]);
      o[nf] = MFMA16(pa1, v1, o[nf]);
    }
    asm volatile("s_waitcnt lgkmcnt(0)\ns_barrier" ::: "memory");
  }

  float inv[4];
#pragma unroll
  for (int r = 0; r < 4; ++r) inv[r] = (lf[r] > 0.f) ? 1.0f / lf[r] : 0.0f;
  ushort* crow = ctxout + ((size_t)bh * 2048 + q0) * 64;
#pragma unroll
  for (int nf = 0; nf < 4; ++nf)
#pragma unroll
    for (int r = 0; r < 4; ++r)
      crow[(size_t)(quad * 4 + r) * 64 + nf * 16 + lane15] = f2bf_rne(o[nf][r] * inv[r]);
}

// ---------------------------------------------------------------------------
extern "C" void kernel_launch(void* const* d_in, const int* in_sizes, int n_in,
                              void* d_out, int out_size, void* d_ws, size_t ws_size,
                              hipStream_t stream) {
  const float* Q = (const float*)d_in[0];
  const float* K = (const float*)d_in[1];
  const float* V = (const float*)d_in[2];
  const float* Wq = (const float*)d_in[3];
  const float* bq = (const float*)d_in[4];
  const float* Wk = (const float*)d_in[5];
  const float* bk = (const float*)d_in[6];
  const float* Wv = (const float*)d_in[7];
  const float* bv = (const float*)d_in[8];
  const float* Wo = (const float*)d_in[9];
  const float* bo = (const float*)d_in[10];
  float* out = (float*)d_out;
  ushort* ws = (ushort*)d_ws;

  if (ws_size >= (58ull << 20)) {
    // big path (58 MB, u16 units):
    // [Qh 4M][Kh 4M][Vt 4M][Bt 3M (X 4M aliases)][WoB 1M @16M][Qb 4M][Kb 4M][Vb 4M]
    ushort* Qh = ws;
    ushort* Kh = Qh + (4 << 20);
    ushort* Vt = Kh + (4 << 20);
    ushort* BtQ = Vt + (4 << 20);
    ushort* BtK = BtQ + (1 << 20);
    ushort* BtV = BtK + (1 << 20);
    ushort* X = BtQ;  // 4M; Bt dead after proj3
    ushort* WoB = ws + (16ull << 20);
    ushort* Qb = WoB + (1 << 20);
    ushort* Kb = Qb + (4 << 20);
    ushort* Vb = Kb + (4 << 20);

    prep_kernel<<<dim3(7424), 256, 0, stream>>>(Q, K, V, Wo, Wq, Wk, Wv, Qb, Kb, Vb,
                                                WoB, BtQ, BtK, BtV);
    proj3_kernel<<<dim3(8, 32, 3), 256, 0, stream>>>(Qb, Kb, Vb, BtQ, BtK, BtV, bq, bk,
                                                     bv, Qh, Kh, Vt);
    attn_kernel<<<dim3(32, 32), 256, 0, stream>>>(Qh, Kh, Vt, X);
    gemm_bt_kernel<<<dim3(8, 32), 256, 0, stream>>>(X, WoB, bo, out);
  } else {
    // fallback (32 MB): f32 A/B staging in the GEMMs
    ushort* Qh = ws;
    ushort* Kh = Qh + (4 << 20);
    ushort* Vt = Kh + (4 << 20);
    ushort* R = Vt + (4 << 20);
    ushort* BtQ = R;
    ushort* BtK = R + (1 << 20);
    ushort* BtV = R + (2 << 20);
    ushort* X = R;

    repack_w_kernel<<<dim3(16, 16, 3), 256, 0, stream>>>(Wq, Wk, Wv, BtQ, BtK, BtV);
    proj3f_kernel<<<dim3(8, 32, 3), 256, 0, stream>>>(Q, K, V, BtQ, BtK, BtV, bq, bk, bv,
                                                      Qh, Kh, Vt);
    attn_kernel<<<dim3(32, 32), 256, 0, stream>>>(Qh, Kh, Vt, X);
    gemm_btf_kernel<<<dim3(8, 32), 256, 0, stream>>>(X, Wo, bo, out);
  }
}

// Round 7
// 228.802 us; speedup vs baseline: 1.0647x; 1.0647x over previous
//
#include <hip/hip_runtime.h>
#include <stdint.h>

typedef __attribute__((ext_vector_type(8))) short short8;
typedef __attribute__((ext_vector_type(4))) short short4v;
typedef __attribute__((ext_vector_type(4))) float float4v;

#define MFMA16(a, b, c) __builtin_amdgcn_mfma_f32_16x16x32_bf16((a), (b), (c), 0, 0, 0)

__device__ __forceinline__ ushort f2bf_rne(float f) {
  union { float f; unsigned u; } x; x.f = f;
  unsigned r = x.u + 0x7FFFu + ((x.u >> 16) & 1u);
  return (ushort)(r >> 16);
}
__device__ __forceinline__ ushort f2bf_trunc(float f) {
  union { float f; unsigned u; } x; x.f = f;
  return (ushort)(x.u >> 16);
}
__device__ __forceinline__ void gload16(const ushort* g, ushort* lds) {
  __builtin_amdgcn_global_load_lds(
      (__attribute__((address_space(1))) unsigned int*)g,
      (__attribute__((address_space(3))) unsigned int*)lds, 16, 0, 0);
}

// scale*log2(e): baked into Qh so attention uses raw exp2 on scores.
#define CEXP 0.1803368801111204f

// ---------------------------------------------------------------------------
// 64x64 transpose (f32 in, bf16 out): out[c*os + r] = bf16(in[r*is + c])
// ---------------------------------------------------------------------------
__device__ __forceinline__ void transpose64f(const float* __restrict__ in, int is,
                                             ushort* __restrict__ out, int os,
                                             ushort* lds /*64*72*/) {
  const int t = threadIdx.x;
#pragma unroll
  for (int it = 0; it < 2; ++it) {
    int e = it * 2048 + t * 8;
    int r = e >> 6, c = e & 63;
    const float* p = in + (size_t)r * is + c;
    float4 x0 = *(const float4*)p;
    float4 x1 = *(const float4*)(p + 4);
    ushort tv[8] __attribute__((aligned(16))) = {
        f2bf_rne(x0.x), f2bf_rne(x0.y), f2bf_rne(x0.z), f2bf_rne(x0.w),
        f2bf_rne(x1.x), f2bf_rne(x1.y), f2bf_rne(x1.z), f2bf_rne(x1.w)};
    *(uint4*)&lds[r * 72 + c] = *(const uint4*)tv;
  }
  __syncthreads();
  const int cc = t >> 2;
  const int rg = (t & 3) * 16;
  ushort tmp[16] __attribute__((aligned(16)));
#pragma unroll
  for (int i = 0; i < 16; ++i) tmp[i] = lds[(rg + i) * 72 + cc];
  *(uint4*)&out[(size_t)cc * os + rg] = *(const uint4*)&tmp[0];
  *(uint4*)&out[(size_t)cc * os + rg + 8] = *(const uint4*)&tmp[8];
}

// ---------------------------------------------------------------------------
// prep: f32->bf16 convert of Q,K,V (4M each) + Wo (1M), and Wq/Wk/Wv repack.
// grid.x = 6144 (QKV) + 512 (Wo) + 768 (repack) = 7424
// ---------------------------------------------------------------------------
__global__ __launch_bounds__(256) void prep_kernel(
    const float* __restrict__ Q, const float* __restrict__ K,
    const float* __restrict__ V, const float* __restrict__ Wo,
    const float* __restrict__ Wq, const float* __restrict__ Wk,
    const float* __restrict__ Wv, ushort* __restrict__ Qb, ushort* __restrict__ Kb,
    ushort* __restrict__ Vb, ushort* __restrict__ WoB, ushort* __restrict__ BtQ,
    ushort* __restrict__ BtK, ushort* __restrict__ BtV) {
  __shared__ ushort lds[64 * 72];
  const int bx = blockIdx.x;
  if (bx < 6656) {
    const float* s;
    ushort* d;
    int i;
    if (bx < 6144) {
      const int plane = bx >> 11;
      s = plane == 0 ? Q : (plane == 1 ? K : V);
      d = plane == 0 ? Qb : (plane == 1 ? Kb : Vb);
      i = ((bx & 2047) * 256 + threadIdx.x) * 8;
    } else {
      s = Wo;
      d = WoB;
      i = ((bx - 6144) * 256 + threadIdx.x) * 8;
    }
    float4 a = *(const float4*)(s + i);
    float4 b = *(const float4*)(s + i + 4);
    ushort t[8] __attribute__((aligned(16))) = {
        f2bf_rne(a.x), f2bf_rne(a.y), f2bf_rne(a.z), f2bf_rne(a.w),
        f2bf_rne(b.x), f2bf_rne(b.y), f2bf_rne(b.z), f2bf_rne(b.w)};
    *(uint4*)(d + i) = *(const uint4*)t;
  } else {
    const int rb = bx - 6656;
    const int dt = rb & 15, h = (rb >> 4) & 15, z = rb >> 8;
    const float* W = z == 0 ? Wq : (z == 1 ? Wk : Wv);
    ushort* Bt = z == 0 ? BtQ : (z == 1 ? BtK : BtV);
    transpose64f(W + h * 65536 + dt * 4096, 64, Bt + h * 65536 + dt * 64, 1024, lds);
  }
}

// standalone repack for the fallback path
__global__ __launch_bounds__(256, 2) void repack_w_kernel(
    const float* __restrict__ Wq, const float* __restrict__ Wk,
    const float* __restrict__ Wv, ushort* __restrict__ BtQ, ushort* __restrict__ BtK,
    ushort* __restrict__ BtV) {
  __shared__ ushort lds[64 * 72];
  const float* W = blockIdx.z == 0 ? Wq : (blockIdx.z == 1 ? Wk : Wv);
  ushort* Bt = blockIdx.z == 0 ? BtQ : (blockIdx.z == 1 ? BtK : BtV);
  const int h = blockIdx.y, dt = blockIdx.x;
  transpose64f(W + h * 65536 + dt * 4096, 64, Bt + h * 65536 + dt * 64, 1024, lds);
}

// ---------------------------------------------------------------------------
// Basic 2-barrier GEMM: C = (A[M,K] @ Bt[N,K]^T + bias)*ascale.
// cmode: 0 bf16 row-major, 1 bf16 scatter Vt (fallback only), 2 f32 row-major,
//        3 bf16 coalesced-transpose into Vt[b,h,dk,t] (needs lA >= 5120 u16).
// ---------------------------------------------------------------------------
template <int F32>
__device__ __forceinline__ void stage16(const void* G, size_t eoff, ushort* ldst) {
  if (F32) {
    const float* p = (const float*)G + eoff;
    float4 x0 = *(const float4*)p;
    float4 x1 = *(const float4*)(p + 4);
    ushort t[8] __attribute__((aligned(16))) = {
        f2bf_rne(x0.x), f2bf_rne(x0.y), f2bf_rne(x0.z), f2bf_rne(x0.w),
        f2bf_rne(x1.x), f2bf_rne(x1.y), f2bf_rne(x1.z), f2bf_rne(x1.w)};
    *(uint4*)ldst = *(const uint4*)t;
  } else {
    gload16((const ushort*)G + eoff, ldst);
  }
}

template <int AF32, int BF32>
__device__ __forceinline__ void gemm_body_basic(const void* __restrict__ A,
                                                const void* __restrict__ Bt,
                                                const float* __restrict__ bias,
                                                void* __restrict__ C, int cmode,
                                                float ascale, int N, int K, ushort* lA,
                                                ushort* lB) {
  const int tid = threadIdx.x;
  const int l = tid & 63, lane15 = l & 15, quad = l >> 4;
  const int mbase = blockIdx.y * 128, nbase = blockIdx.x * 128;
  const int w = tid >> 6;
  const int wrow = (w >> 1) * 64, wcol = (w & 1) * 64;
  const int e0 = tid * 8;
  const int e1 = 2048 + tid * 8;
  const int r0 = e0 >> 5, c0 = e0 & 31;
  const int r1 = e1 >> 5, c1 = e1 & 31;

  float4v acc[4][4];
#pragma unroll
  for (int i = 0; i < 4; ++i)
#pragma unroll
    for (int j = 0; j < 4; ++j) acc[i][j] = (float4v){0.f, 0.f, 0.f, 0.f};

  for (int kb = 0; kb < K; kb += 32) {
    __syncthreads();
    stage16<AF32>(A, (size_t)(mbase + r0) * K + c0 + kb, &lA[e0]);
    stage16<AF32>(A, (size_t)(mbase + r1) * K + c1 + kb, &lA[e1]);
    stage16<BF32>(Bt, (size_t)(nbase + r0) * K + c0 + kb, &lB[e0]);
    stage16<BF32>(Bt, (size_t)(nbase + r1) * K + c1 + kb, &lB[e1]);
    asm volatile("s_waitcnt vmcnt(0)" ::: "memory");
    __syncthreads();
    short8 a[4], b[4];
#pragma unroll
    for (int i = 0; i < 4; ++i) {
      a[i] = *(const short8*)&lA[(wrow + i * 16 + lane15) * 32 + quad * 8];
      b[i] = *(const short8*)&lB[(wcol + i * 16 + lane15) * 32 + quad * 8];
    }
#pragma unroll
    for (int i = 0; i < 4; ++i)
#pragma unroll
      for (int j = 0; j < 4; ++j) acc[i][j] = MFMA16(a[i], b[j], acc[i][j]);
  }

  if (cmode == 3) {
    // coalesced transposed epilogue into Vt[b,h,dk,t] via per-wave LDS scratch
    __syncthreads();
    uint* sp = (uint*)lA + w * 576;  // 2304 B/wave, lA must be >= 10240 B
    const int bb = mbase >> 11;
    const int tb = (mbase & 2047) + wrow;
#pragma unroll
    for (int j = 0; j < 4; ++j) {
      {
        const int n = nbase + wcol + j * 16 + lane15;
        const float bvs = bias[n];
#pragma unroll
        for (int i = 0; i < 4; ++i)
#pragma unroll
          for (int rp = 0; rp < 2; ++rp) {
            const uint lo = f2bf_rne((acc[i][j][2 * rp] + bvs) * ascale);
            const uint hi = f2bf_rne((acc[i][j][2 * rp + 1] + bvs) * ascale);
            sp[36 * lane15 + i * 8 + quad * 2 + rp] = lo | (hi << 16);
          }
      }
#pragma unroll
      for (int t = 0; t < 2; ++t) {
        const int row = t * 8 + (l >> 3);
        const int c = l & 7;
        uint4 d = *(const uint4*)(sp + 36 * row + 4 * c);
        const int ng = nbase + wcol + j * 16 + row;
        ushort* dst = (ushort*)C + ((size_t)(bb * 1024 + ng)) * 2048 + tb + c * 8;
        *(uint4*)dst = d;
      }
    }
    return;
  }

#pragma unroll
  for (int j = 0; j < 4; ++j) {
    const int n = nbase + wcol + j * 16 + lane15;
    const float bvs = bias[n];
#pragma unroll
    for (int i = 0; i < 4; ++i) {
      const int m0 = mbase + wrow + i * 16 + quad * 4;
#pragma unroll
      for (int r = 0; r < 4; ++r) {
        const float val = (acc[i][j][r] + bvs) * ascale;
        if (cmode == 1) {
          const int m = m0 + r;
          const int bb = m >> 11, t = m & 2047;
          ((ushort*)C)[((size_t)(bb * 1024 + n)) * 2048 + t] = f2bf_rne(val);
        } else if (cmode == 2) {
          ((float*)C)[(size_t)(m0 + r) * N + n] = val;
        } else {
          ((ushort*)C)[(size_t)(m0 + r) * N + n] = f2bf_rne(val);
        }
      }
    }
  }
}

// main-path projections (bf16 operands, coalesced Vt epilogue)
__global__ __launch_bounds__(256, 2) void proj3_kernel(
    const ushort* __restrict__ Qb, const ushort* __restrict__ Kb,
    const ushort* __restrict__ Vb, const ushort* __restrict__ BtQ,
    const ushort* __restrict__ BtK, const ushort* __restrict__ BtV,
    const float* __restrict__ bq, const float* __restrict__ bk,
    const float* __restrict__ bv, ushort* __restrict__ Qh, ushort* __restrict__ Kh,
    ushort* __restrict__ Vt) {
  __shared__ ushort lA[5120], lB[4096];
  if (blockIdx.z == 0)
    gemm_body_basic<0, 0>(Qb, BtQ, bq, Qh, 0, CEXP, 1024, 1024, lA, lB);
  else if (blockIdx.z == 1)
    gemm_body_basic<0, 0>(Kb, BtK, bk, Kh, 0, 1.0f, 1024, 1024, lA, lB);
  else
    gemm_body_basic<0, 0>(Vb, BtV, bv, Vt, 3, 1.0f, 1024, 1024, lA, lB);
}

// ---------------------------------------------------------------------------
// Output projection: 128(M)x64(N) tiles -> grid (16,32) = 512 blocks (2/CU so
// the vmcnt(0)+barrier drains overlap across co-resident blocks).
// Wave wv covers rows wv*32..wv*32+32, all 64 cols. acc[2][4]. f32 out.
// ---------------------------------------------------------------------------
__global__ __launch_bounds__(256, 2) void gemm_out_kernel(
    const ushort* __restrict__ X, const ushort* __restrict__ WoB,
    const float* __restrict__ bo, float* __restrict__ out) {
  __shared__ ushort lA[4096], lB[2048];
  const int tid = threadIdx.x;
  const int l = tid & 63, lane15 = l & 15, quad = l >> 4;
  const int mbase = blockIdx.y * 128, nbase = blockIdx.x * 64;
  const int wv = tid >> 6;
  const int wrow = wv * 32;
  const int e0 = tid * 8;
  const int e1 = 2048 + tid * 8;
  const int r0 = e0 >> 5, c0 = e0 & 31;
  const int r1 = e1 >> 5, c1 = e1 & 31;
  const ushort* Ag0 = X + (size_t)(mbase + r0) * 1024 + c0;
  const ushort* Ag1 = X + (size_t)(mbase + r1) * 1024 + c1;
  const ushort* Bg0 = WoB + (size_t)(nbase + r0) * 1024 + c0;

  float4v acc[2][4];
#pragma unroll
  for (int i = 0; i < 2; ++i)
#pragma unroll
    for (int j = 0; j < 4; ++j) acc[i][j] = (float4v){0.f, 0.f, 0.f, 0.f};

  for (int kb = 0; kb < 1024; kb += 32) {
    __syncthreads();
    gload16(Ag0 + kb, &lA[e0]);
    gload16(Ag1 + kb, &lA[e1]);
    gload16(Bg0 + kb, &lB[e0]);
    asm volatile("s_waitcnt vmcnt(0)" ::: "memory");
    __syncthreads();
    short8 a[2], b[4];
#pragma unroll
    for (int i = 0; i < 2; ++i)
      a[i] = *(const short8*)&lA[(wrow + i * 16 + lane15) * 32 + quad * 8];
#pragma unroll
    for (int j = 0; j < 4; ++j)
      b[j] = *(const short8*)&lB[(j * 16 + lane15) * 32 + quad * 8];
#pragma unroll
    for (int i = 0; i < 2; ++i)
#pragma unroll
      for (int j = 0; j < 4; ++j) acc[i][j] = MFMA16(a[i], b[j], acc[i][j]);
  }

#pragma unroll
  for (int j = 0; j < 4; ++j) {
    const int n = nbase + j * 16 + lane15;
    const float bvs = bo[n];
#pragma unroll
    for (int i = 0; i < 2; ++i) {
      const int m0 = mbase + wrow + i * 16 + quad * 4;
#pragma unroll
      for (int r = 0; r < 4; ++r) out[(size_t)(m0 + r) * 1024 + n] = acc[i][j][r] + bvs;
    }
  }
}

// fallback-path kernels (f32 operands)
__global__ __launch_bounds__(256, 2) void proj3f_kernel(
    const float* __restrict__ Q, const float* __restrict__ Kin,
    const float* __restrict__ V, const ushort* __restrict__ BtQ,
    const ushort* __restrict__ BtK, const ushort* __restrict__ BtV,
    const float* __restrict__ bq, const float* __restrict__ bk,
    const float* __restrict__ bv, ushort* __restrict__ Qh, ushort* __restrict__ Kh,
    ushort* __restrict__ Vt) {
  __shared__ ushort lA[5120], lB[4096];
  if (blockIdx.z == 0)
    gemm_body_basic<1, 0>(Q, BtQ, bq, Qh, 0, CEXP, 1024, 1024, lA, lB);
  else if (blockIdx.z == 1)
    gemm_body_basic<1, 0>(Kin, BtK, bk, Kh, 0, 1.0f, 1024, 1024, lA, lB);
  else
    gemm_body_basic<1, 0>(V, BtV, bv, Vt, 3, 1.0f, 1024, 1024, lA, lB);
}

__global__ __launch_bounds__(256, 2) void gemm_btf_kernel(
    const ushort* __restrict__ X, const float* __restrict__ Wo,
    const float* __restrict__ bo, float* __restrict__ out) {
  __shared__ ushort lA[5120], lB[4096];
  gemm_body_basic<0, 1>(X, Wo, bo, out, 2, 1.0f, 1024, 1024, lA, lB);
}

// ---------------------------------------------------------------------------
// Flash attention (round-5 exact): grid (bh=32, qtile=32), XCD-local K/V,
// single-buffer LDS tiles via global_load_lds, XOR-swizzled layout, no-max
// exp2 softmax, rowsum-by-MFMA, wave-private P transpose through LDS.
// ---------------------------------------------------------------------------
__global__ __launch_bounds__(256, 4) void attn_kernel(const ushort* __restrict__ Qh,
                                                      const ushort* __restrict__ Kh,
                                                      const ushort* __restrict__ Vt,
                                                      ushort* __restrict__ ctxout) {
  __shared__ ushort lK[64 * 64];
  __shared__ ushort lV[64 * 64];
  __shared__ ushort pl_all[4][16 * 68];
  const int tid = threadIdx.x, l = tid & 63, wv = tid >> 6;
  const int lane15 = l & 15, quad = l >> 4;
  const int bh = blockIdx.x, b = bh >> 4, h = bh & 15;
  const int q0 = blockIdx.y * 64 + wv * 16;

  const int sr = tid >> 3;
  const int scb = (tid & 7) ^ (sr & 7);
  const ushort* Kp = Kh + (size_t)(b * 2048) * 1024 + h * 64;
  const ushort* Vp = Vt + (size_t)(bh * 64) * 2048;
  const ushort* Kg0 = Kp + (size_t)sr * 1024 + scb * 8;
  const ushort* Kg1 = Kg0 + 32 * 1024;
  const ushort* Vg0 = Vp + (size_t)sr * 2048 + scb * 8;
  const ushort* Vg1 = Vg0 + 32 * 2048;
  ushort* lKd0 = lK + tid * 8;
  ushort* lKd1 = lK + 2048 + tid * 8;
  ushort* lVd0 = lV + tid * 8;
  ushort* lVd1 = lV + 2048 + tid * 8;

  const ushort* qrow = Qh + (size_t)(b * 2048 + q0 + lane15) * 1024 + h * 64;
  const short8 qa0 = *(const short8*)&qrow[quad * 8];
  const short8 qa1 = *(const short8*)&qrow[32 + quad * 8];

  const int xm = lane15 & 7;
  const int fr0 = lane15 * 64 + ((quad ^ xm) * 8);
  const int fr1 = lane15 * 64 + (((quad + 4) ^ xm) * 8);

  ushort* pl = &pl_all[wv][0];
  const short8 ones = {0x3F80, 0x3F80, 0x3F80, 0x3F80, 0x3F80, 0x3F80, 0x3F80, 0x3F80};

  float4v o[4];
  float4v lf = (float4v){0.f, 0.f, 0.f, 0.f};
#pragma unroll
  for (int i = 0; i < 4; ++i) o[i] = (float4v){0.f, 0.f, 0.f, 0.f};

  for (int s0 = 0; s0 < 2048; s0 += 64) {
    __syncthreads();
    gload16(Kg0 + (size_t)s0 * 1024, lKd0);
    gload16(Kg1 + (size_t)s0 * 1024, lKd1);
    gload16(Vg0 + s0, lVd0);
    gload16(Vg1 + s0, lVd1);
    asm volatile("s_waitcnt vmcnt(0)" ::: "memory");
    __syncthreads();

    float4v sb[4];
#pragma unroll
    for (int i = 0; i < 4; ++i) {
      short8 k0 = *(const short8*)&lK[i * 1024 + fr0];
      short8 k1 = *(const short8*)&lK[i * 1024 + fr1];
      float4v c = (float4v){0.f, 0.f, 0.f, 0.f};
      c = MFMA16(qa0, k0, c);
      c = MFMA16(qa1, k1, c);
      sb[i] = c;
    }
#pragma unroll
    for (int i = 0; i < 4; ++i)
#pragma unroll
      for (int r = 0; r < 4; ++r)
        pl[(quad * 4 + r) * 68 + i * 16 + lane15] =
            f2bf_trunc(__builtin_amdgcn_exp2f(sb[i][r]));
    short4v p0a = *(const short4v*)&pl[lane15 * 68 + quad * 8];
    short4v p0b = *(const short4v*)&pl[lane15 * 68 + quad * 8 + 4];
    short4v p1a = *(const short4v*)&pl[lane15 * 68 + 32 + quad * 8];
    short4v p1b = *(const short4v*)&pl[lane15 * 68 + 32 + quad * 8 + 4];
    short8 pa0 = __builtin_shufflevector(p0a, p0b, 0, 1, 2, 3, 4, 5, 6, 7);
    short8 pa1 = __builtin_shufflevector(p1a, p1b, 0, 1, 2, 3, 4, 5, 6, 7);
    lf = MFMA16(pa0, ones, lf);
    lf = MFMA16(pa1, ones, lf);
#pragma unroll
    for (int nf = 0; nf < 4; ++nf) {
      short8 v0 = *(const short8*)&lV[nf * 1024 + fr0];
      short8 v1 = *(const short8*)&lV[nf * 1024 + fr1];
      o[nf] = MFMA16(pa0, v0, o[nf]);
      o[nf] = MFMA16(pa1, v1, o[nf]);
    }
  }

  float inv[4];
#pragma unroll
  for (int r = 0; r < 4; ++r) inv[r] = (lf[r] > 0.f) ? 1.0f / lf[r] : 0.0f;
  ushort* crow = ctxout + ((size_t)bh * 2048 + q0) * 64;
#pragma unroll
  for (int nf = 0; nf < 4; ++nf)
#pragma unroll
    for (int r = 0; r < 4; ++r)
      crow[(size_t)(quad * 4 + r) * 64 + nf * 16 + lane15] = f2bf_rne(o[nf][r] * inv[r]);
}

// ---------------------------------------------------------------------------
extern "C" void kernel_launch(void* const* d_in, const int* in_sizes, int n_in,
                              void* d_out, int out_size, void* d_ws, size_t ws_size,
                              hipStream_t stream) {
  const float* Q = (const float*)d_in[0];
  const float* K = (const float*)d_in[1];
  const float* V = (const float*)d_in[2];
  const float* Wq = (const float*)d_in[3];
  const float* bq = (const float*)d_in[4];
  const float* Wk = (const float*)d_in[5];
  const float* bk = (const float*)d_in[6];
  const float* Wv = (const float*)d_in[7];
  const float* bv = (const float*)d_in[8];
  const float* Wo = (const float*)d_in[9];
  const float* bo = (const float*)d_in[10];
  float* out = (float*)d_out;
  ushort* ws = (ushort*)d_ws;

  if (ws_size >= (58ull << 20)) {
    // big path (58 MB, u16 units):
    // [Qh 4M][Kh 4M][Vt 4M][Bt 3M (X 4M aliases)][WoB 1M @16M][Qb 4M][Kb 4M][Vb 4M]
    ushort* Qh = ws;
    ushort* Kh = Qh + (4 << 20);
    ushort* Vt = Kh + (4 << 20);
    ushort* BtQ = Vt + (4 << 20);
    ushort* BtK = BtQ + (1 << 20);
    ushort* BtV = BtK + (1 << 20);
    ushort* X = BtQ;  // 4M; Bt dead after proj3
    ushort* WoB = ws + (16ull << 20);
    ushort* Qb = WoB + (1 << 20);
    ushort* Kb = Qb + (4 << 20);
    ushort* Vb = Kb + (4 << 20);

    prep_kernel<<<dim3(7424), 256, 0, stream>>>(Q, K, V, Wo, Wq, Wk, Wv, Qb, Kb, Vb,
                                                WoB, BtQ, BtK, BtV);
    proj3_kernel<<<dim3(8, 32, 3), 256, 0, stream>>>(Qb, Kb, Vb, BtQ, BtK, BtV, bq, bk,
                                                     bv, Qh, Kh, Vt);
    attn_kernel<<<dim3(32, 32), 256, 0, stream>>>(Qh, Kh, Vt, X);
    gemm_out_kernel<<<dim3(16, 32), 256, 0, stream>>>(X, WoB, bo, out);
  } else {
    // fallback (32 MB): f32 A/B staging in the GEMMs
    ushort* Qh = ws;
    ushort* Kh = Qh + (4 << 20);
    ushort* Vt = Kh + (4 << 20);
    ushort* R = Vt + (4 << 20);
    ushort* BtQ = R;
    ushort* BtK = R + (1 << 20);
    ushort* BtV = R + (2 << 20);
    ushort* X = R;

    repack_w_kernel<<<dim3(16, 16, 3), 256, 0, stream>>>(Wq, Wk, Wv, BtQ, BtK, BtV);
    proj3f_kernel<<<dim3(8, 32, 3), 256, 0, stream>>>(Q, K, V, BtQ, BtK, BtV, bq, bk, bv,
                                                      Qh, Kh, Vt);
    attn_kernel<<<dim3(32, 32), 256, 0, stream>>>(Qh, Kh, Vt, X);
    gemm_btf_kernel<<<dim3(8, 32), 256, 0, stream>>>(X, Wo, bo, out);
  }
}

// Round 8
// 225.674 us; speedup vs baseline: 1.0794x; 1.0139x over previous
//
#include <hip/hip_runtime.h>
#include <stdint.h>

typedef __attribute__((ext_vector_type(8))) short short8;
typedef __attribute__((ext_vector_type(4))) short short4v;
typedef __attribute__((ext_vector_type(4))) float float4v;

#define MFMA16(a, b, c) __builtin_amdgcn_mfma_f32_16x16x32_bf16((a), (b), (c), 0, 0, 0)

__device__ __forceinline__ ushort f2bf_rne(float f) {
  union { float f; unsigned u; } x; x.f = f;
  unsigned r = x.u + 0x7FFFu + ((x.u >> 16) & 1u);
  return (ushort)(r >> 16);
}
__device__ __forceinline__ ushort f2bf_trunc(float f) {
  union { float f; unsigned u; } x; x.f = f;
  return (ushort)(x.u >> 16);
}
__device__ __forceinline__ void gload16(const ushort* g, ushort* lds) {
  __builtin_amdgcn_global_load_lds(
      (__attribute__((address_space(1))) unsigned int*)g,
      (__attribute__((address_space(3))) unsigned int*)lds, 16, 0, 0);
}

// scale*log2(e): baked into Qh so attention uses raw exp2 on scores.
#define CEXP 0.1803368801111204f

// ---------------------------------------------------------------------------
// 64x64 transpose (f32 in, bf16 out): out[c*os + r] = bf16(in[r*is + c])
// ---------------------------------------------------------------------------
__device__ __forceinline__ void transpose64f(const float* __restrict__ in, int is,
                                             ushort* __restrict__ out, int os,
                                             ushort* lds /*64*72*/) {
  const int t = threadIdx.x;
#pragma unroll
  for (int it = 0; it < 2; ++it) {
    int e = it * 2048 + t * 8;
    int r = e >> 6, c = e & 63;
    const float* p = in + (size_t)r * is + c;
    float4 x0 = *(const float4*)p;
    float4 x1 = *(const float4*)(p + 4);
    ushort tv[8] __attribute__((aligned(16))) = {
        f2bf_rne(x0.x), f2bf_rne(x0.y), f2bf_rne(x0.z), f2bf_rne(x0.w),
        f2bf_rne(x1.x), f2bf_rne(x1.y), f2bf_rne(x1.z), f2bf_rne(x1.w)};
    *(uint4*)&lds[r * 72 + c] = *(const uint4*)tv;
  }
  __syncthreads();
  const int cc = t >> 2;
  const int rg = (t & 3) * 16;
  ushort tmp[16] __attribute__((aligned(16)));
#pragma unroll
  for (int i = 0; i < 16; ++i) tmp[i] = lds[(rg + i) * 72 + cc];
  *(uint4*)&out[(size_t)cc * os + rg] = *(const uint4*)&tmp[0];
  *(uint4*)&out[(size_t)cc * os + rg + 8] = *(const uint4*)&tmp[8];
}

// ---------------------------------------------------------------------------
// prep: f32->bf16 convert of Q,K,V (4M each) + Wo (1M), and Wq/Wk/Wv repack.
// grid.x = 6144 (QKV) + 512 (Wo) + 768 (repack) = 7424
// ---------------------------------------------------------------------------
__global__ __launch_bounds__(256) void prep_kernel(
    const float* __restrict__ Q, const float* __restrict__ K,
    const float* __restrict__ V, const float* __restrict__ Wo,
    const float* __restrict__ Wq, const float* __restrict__ Wk,
    const float* __restrict__ Wv, ushort* __restrict__ Qb, ushort* __restrict__ Kb,
    ushort* __restrict__ Vb, ushort* __restrict__ WoB, ushort* __restrict__ BtQ,
    ushort* __restrict__ BtK, ushort* __restrict__ BtV) {
  __shared__ ushort lds[64 * 72];
  const int bx = blockIdx.x;
  if (bx < 6656) {
    const float* s;
    ushort* d;
    int i;
    if (bx < 6144) {
      const int plane = bx >> 11;
      s = plane == 0 ? Q : (plane == 1 ? K : V);
      d = plane == 0 ? Qb : (plane == 1 ? Kb : Vb);
      i = ((bx & 2047) * 256 + threadIdx.x) * 8;
    } else {
      s = Wo;
      d = WoB;
      i = ((bx - 6144) * 256 + threadIdx.x) * 8;
    }
    float4 a = *(const float4*)(s + i);
    float4 b = *(const float4*)(s + i + 4);
    ushort t[8] __attribute__((aligned(16))) = {
        f2bf_rne(a.x), f2bf_rne(a.y), f2bf_rne(a.z), f2bf_rne(a.w),
        f2bf_rne(b.x), f2bf_rne(b.y), f2bf_rne(b.z), f2bf_rne(b.w)};
    *(uint4*)(d + i) = *(const uint4*)t;
  } else {
    const int rb = bx - 6656;
    const int dt = rb & 15, h = (rb >> 4) & 15, z = rb >> 8;
    const float* W = z == 0 ? Wq : (z == 1 ? Wk : Wv);
    ushort* Bt = z == 0 ? BtQ : (z == 1 ? BtK : BtV);
    transpose64f(W + h * 65536 + dt * 4096, 64, Bt + h * 65536 + dt * 64, 1024, lds);
  }
}

// standalone repack for the fallback path
__global__ __launch_bounds__(256, 2) void repack_w_kernel(
    const float* __restrict__ Wq, const float* __restrict__ Wk,
    const float* __restrict__ Wv, ushort* __restrict__ BtQ, ushort* __restrict__ BtK,
    ushort* __restrict__ BtV) {
  __shared__ ushort lds[64 * 72];
  const float* W = blockIdx.z == 0 ? Wq : (blockIdx.z == 1 ? Wk : Wv);
  ushort* Bt = blockIdx.z == 0 ? BtQ : (blockIdx.z == 1 ? BtK : BtV);
  const int h = blockIdx.y, dt = blockIdx.x;
  transpose64f(W + h * 65536 + dt * 4096, 64, Bt + h * 65536 + dt * 64, 1024, lds);
}

// ---------------------------------------------------------------------------
// Basic 2-barrier GEMM: C = (A[M,K] @ Bt[N,K]^T + bias)*ascale.
// cmode: 0 bf16 row-major, 1 bf16 scatter Vt (fallback only), 2 f32 row-major,
//        3 bf16 coalesced-transpose into Vt[b,h,dk,t] (needs lA >= 5120 u16).
// ---------------------------------------------------------------------------
template <int F32>
__device__ __forceinline__ void stage16(const void* G, size_t eoff, ushort* ldst) {
  if (F32) {
    const float* p = (const float*)G + eoff;
    float4 x0 = *(const float4*)p;
    float4 x1 = *(const float4*)(p + 4);
    ushort t[8] __attribute__((aligned(16))) = {
        f2bf_rne(x0.x), f2bf_rne(x0.y), f2bf_rne(x0.z), f2bf_rne(x0.w),
        f2bf_rne(x1.x), f2bf_rne(x1.y), f2bf_rne(x1.z), f2bf_rne(x1.w)};
    *(uint4*)ldst = *(const uint4*)t;
  } else {
    gload16((const ushort*)G + eoff, ldst);
  }
}

template <int AF32, int BF32>
__device__ __forceinline__ void gemm_body_basic(const void* __restrict__ A,
                                                const void* __restrict__ Bt,
                                                const float* __restrict__ bias,
                                                void* __restrict__ C, int cmode,
                                                float ascale, int N, int K, ushort* lA,
                                                ushort* lB) {
  const int tid = threadIdx.x;
  const int l = tid & 63, lane15 = l & 15, quad = l >> 4;
  const int mbase = blockIdx.y * 128, nbase = blockIdx.x * 128;
  const int w = tid >> 6;
  const int wrow = (w >> 1) * 64, wcol = (w & 1) * 64;
  const int e0 = tid * 8;
  const int e1 = 2048 + tid * 8;
  const int r0 = e0 >> 5, c0 = e0 & 31;
  const int r1 = e1 >> 5, c1 = e1 & 31;

  float4v acc[4][4];
#pragma unroll
  for (int i = 0; i < 4; ++i)
#pragma unroll
    for (int j = 0; j < 4; ++j) acc[i][j] = (float4v){0.f, 0.f, 0.f, 0.f};

  for (int kb = 0; kb < K; kb += 32) {
    __syncthreads();
    stage16<AF32>(A, (size_t)(mbase + r0) * K + c0 + kb, &lA[e0]);
    stage16<AF32>(A, (size_t)(mbase + r1) * K + c1 + kb, &lA[e1]);
    stage16<BF32>(Bt, (size_t)(nbase + r0) * K + c0 + kb, &lB[e0]);
    stage16<BF32>(Bt, (size_t)(nbase + r1) * K + c1 + kb, &lB[e1]);
    asm volatile("s_waitcnt vmcnt(0)" ::: "memory");
    __syncthreads();
    short8 a[4], b[4];
#pragma unroll
    for (int i = 0; i < 4; ++i) {
      a[i] = *(const short8*)&lA[(wrow + i * 16 + lane15) * 32 + quad * 8];
      b[i] = *(const short8*)&lB[(wcol + i * 16 + lane15) * 32 + quad * 8];
    }
#pragma unroll
    for (int i = 0; i < 4; ++i)
#pragma unroll
      for (int j = 0; j < 4; ++j) acc[i][j] = MFMA16(a[i], b[j], acc[i][j]);
  }

  if (cmode == 3) {
    // coalesced transposed epilogue into Vt[b,h,dk,t] via per-wave LDS scratch
    __syncthreads();
    uint* sp = (uint*)lA + w * 576;  // 2304 B/wave, lA must be >= 10240 B
    const int bb = mbase >> 11;
    const int tb = (mbase & 2047) + wrow;
#pragma unroll
    for (int j = 0; j < 4; ++j) {
      {
        const int n = nbase + wcol + j * 16 + lane15;
        const float bvs = bias[n];
#pragma unroll
        for (int i = 0; i < 4; ++i)
#pragma unroll
          for (int rp = 0; rp < 2; ++rp) {
            const uint lo = f2bf_rne((acc[i][j][2 * rp] + bvs) * ascale);
            const uint hi = f2bf_rne((acc[i][j][2 * rp + 1] + bvs) * ascale);
            sp[36 * lane15 + i * 8 + quad * 2 + rp] = lo | (hi << 16);
          }
      }
#pragma unroll
      for (int t = 0; t < 2; ++t) {
        const int row = t * 8 + (l >> 3);
        const int c = l & 7;
        uint4 d = *(const uint4*)(sp + 36 * row + 4 * c);
        const int ng = nbase + wcol + j * 16 + row;
        ushort* dst = (ushort*)C + ((size_t)(bb * 1024 + ng)) * 2048 + tb + c * 8;
        *(uint4*)dst = d;
      }
    }
    return;
  }

#pragma unroll
  for (int j = 0; j < 4; ++j) {
    const int n = nbase + wcol + j * 16 + lane15;
    const float bvs = bias[n];
#pragma unroll
    for (int i = 0; i < 4; ++i) {
      const int m0 = mbase + wrow + i * 16 + quad * 4;
#pragma unroll
      for (int r = 0; r < 4; ++r) {
        const float val = (acc[i][j][r] + bvs) * ascale;
        if (cmode == 1) {
          const int m = m0 + r;
          const int bb = m >> 11, t = m & 2047;
          ((ushort*)C)[((size_t)(bb * 1024 + n)) * 2048 + t] = f2bf_rne(val);
        } else if (cmode == 2) {
          ((float*)C)[(size_t)(m0 + r) * N + n] = val;
        } else {
          ((ushort*)C)[(size_t)(m0 + r) * N + n] = f2bf_rne(val);
        }
      }
    }
  }
}

// main-path projections (bf16 operands, coalesced Vt epilogue)
__global__ __launch_bounds__(256, 2) void proj3_kernel(
    const ushort* __restrict__ Qb, const ushort* __restrict__ Kb,
    const ushort* __restrict__ Vb, const ushort* __restrict__ BtQ,
    const ushort* __restrict__ BtK, const ushort* __restrict__ BtV,
    const float* __restrict__ bq, const float* __restrict__ bk,
    const float* __restrict__ bv, ushort* __restrict__ Qh, ushort* __restrict__ Kh,
    ushort* __restrict__ Vt) {
  __shared__ ushort lA[5120], lB[4096];
  if (blockIdx.z == 0)
    gemm_body_basic<0, 0>(Qb, BtQ, bq, Qh, 0, CEXP, 1024, 1024, lA, lB);
  else if (blockIdx.z == 1)
    gemm_body_basic<0, 0>(Kb, BtK, bk, Kh, 0, 1.0f, 1024, 1024, lA, lB);
  else
    gemm_body_basic<0, 0>(Vb, BtV, bv, Vt, 3, 1.0f, 1024, 1024, lA, lB);
}

// ---------------------------------------------------------------------------
// Output projection: 128(M)x64(N) tiles -> grid (16,32) = 512 blocks (2/CU).
// ---------------------------------------------------------------------------
__global__ __launch_bounds__(256, 2) void gemm_out_kernel(
    const ushort* __restrict__ X, const ushort* __restrict__ WoB,
    const float* __restrict__ bo, float* __restrict__ out) {
  __shared__ ushort lA[4096], lB[2048];
  const int tid = threadIdx.x;
  const int l = tid & 63, lane15 = l & 15, quad = l >> 4;
  const int mbase = blockIdx.y * 128, nbase = blockIdx.x * 64;
  const int wv = tid >> 6;
  const int wrow = wv * 32;
  const int e0 = tid * 8;
  const int e1 = 2048 + tid * 8;
  const int r0 = e0 >> 5, c0 = e0 & 31;
  const int r1 = e1 >> 5, c1 = e1 & 31;
  const ushort* Ag0 = X + (size_t)(mbase + r0) * 1024 + c0;
  const ushort* Ag1 = X + (size_t)(mbase + r1) * 1024 + c1;
  const ushort* Bg0 = WoB + (size_t)(nbase + r0) * 1024 + c0;

  float4v acc[2][4];
#pragma unroll
  for (int i = 0; i < 2; ++i)
#pragma unroll
    for (int j = 0; j < 4; ++j) acc[i][j] = (float4v){0.f, 0.f, 0.f, 0.f};

  for (int kb = 0; kb < 1024; kb += 32) {
    __syncthreads();
    gload16(Ag0 + kb, &lA[e0]);
    gload16(Ag1 + kb, &lA[e1]);
    gload16(Bg0 + kb, &lB[e0]);
    asm volatile("s_waitcnt vmcnt(0)" ::: "memory");
    __syncthreads();
    short8 a[2], b[4];
#pragma unroll
    for (int i = 0; i < 2; ++i)
      a[i] = *(const short8*)&lA[(wrow + i * 16 + lane15) * 32 + quad * 8];
#pragma unroll
    for (int j = 0; j < 4; ++j)
      b[j] = *(const short8*)&lB[(j * 16 + lane15) * 32 + quad * 8];
#pragma unroll
    for (int i = 0; i < 2; ++i)
#pragma unroll
      for (int j = 0; j < 4; ++j) acc[i][j] = MFMA16(a[i], b[j], acc[i][j]);
  }

#pragma unroll
  for (int j = 0; j < 4; ++j) {
    const int n = nbase + j * 16 + lane15;
    const float bvs = bo[n];
#pragma unroll
    for (int i = 0; i < 2; ++i) {
      const int m0 = mbase + wrow + i * 16 + quad * 4;
#pragma unroll
      for (int r = 0; r < 4; ++r) out[(size_t)(m0 + r) * 1024 + n] = acc[i][j][r] + bvs;
    }
  }
}

// fallback-path kernels (f32 operands)
__global__ __launch_bounds__(256, 2) void proj3f_kernel(
    const float* __restrict__ Q, const float* __restrict__ Kin,
    const float* __restrict__ V, const ushort* __restrict__ BtQ,
    const ushort* __restrict__ BtK, const ushort* __restrict__ BtV,
    const float* __restrict__ bq, const float* __restrict__ bk,
    const float* __restrict__ bv, ushort* __restrict__ Qh, ushort* __restrict__ Kh,
    ushort* __restrict__ Vt) {
  __shared__ ushort lA[5120], lB[4096];
  if (blockIdx.z == 0)
    gemm_body_basic<1, 0>(Q, BtQ, bq, Qh, 0, CEXP, 1024, 1024, lA, lB);
  else if (blockIdx.z == 1)
    gemm_body_basic<1, 0>(Kin, BtK, bk, Kh, 0, 1.0f, 1024, 1024, lA, lB);
  else
    gemm_body_basic<1, 0>(V, BtV, bv, Vt, 3, 1.0f, 1024, 1024, lA, lB);
}

__global__ __launch_bounds__(256, 2) void gemm_btf_kernel(
    const ushort* __restrict__ X, const float* __restrict__ Wo,
    const float* __restrict__ bo, float* __restrict__ out) {
  __shared__ ushort lA[5120], lB[4096];
  gemm_body_basic<0, 1>(X, Wo, bo, out, 2, 1.0f, 1024, 1024, lA, lB);
}

// ---------------------------------------------------------------------------
// Flash attention v4: 512-thread blocks (8 waves), q-tile 128, grid (32 bh,
// 16 qtiles) = 512 blocks = 2/CU, 16 waves/CU. Per-wave inner code identical
// to round-5; K/V tile staging (16 KB/step) now amortized over 2x the q-work,
// halving machine-wide barrier-drain events and DMA bytes per FLOP.
// Each thread stages exactly one 16B chunk of K and one of V per step.
// ---------------------------------------------------------------------------
__global__ __launch_bounds__(512, 4) void attn_kernel(const ushort* __restrict__ Qh,
                                                      const ushort* __restrict__ Kh,
                                                      const ushort* __restrict__ Vt,
                                                      ushort* __restrict__ ctxout) {
  __shared__ ushort lK[64 * 64];
  __shared__ ushort lV[64 * 64];
  __shared__ ushort pl_all[8][16 * 68];
  const int tid = threadIdx.x, l = tid & 63, wv = tid >> 6;
  const int lane15 = l & 15, quad = l >> 4;
  const int bh = blockIdx.x, b = bh >> 4, h = bh & 15;
  const int q0 = blockIdx.y * 128 + wv * 16;

  // staging: thread t fetches (row = t>>3, colblk = (t&7)^(row&7)) of the
  // 64x64 tile; 512 threads cover the full tile in one instruction per array.
  const int sr = tid >> 3;
  const int scb = (tid & 7) ^ (sr & 7);
  const ushort* Kp = Kh + (size_t)(b * 2048) * 1024 + h * 64;
  const ushort* Vp = Vt + (size_t)(bh * 64) * 2048;
  const ushort* Kg = Kp + (size_t)sr * 1024 + scb * 8;
  const ushort* Vg = Vp + (size_t)sr * 2048 + scb * 8;
  ushort* lKd = lK + tid * 8;
  ushort* lVd = lV + tid * 8;

  const ushort* qrow = Qh + (size_t)(b * 2048 + q0 + lane15) * 1024 + h * 64;
  const short8 qa0 = *(const short8*)&qrow[quad * 8];
  const short8 qa1 = *(const short8*)&qrow[32 + quad * 8];

  const int xm = lane15 & 7;
  const int fr0 = lane15 * 64 + ((quad ^ xm) * 8);
  const int fr1 = lane15 * 64 + (((quad + 4) ^ xm) * 8);

  ushort* pl = &pl_all[wv][0];
  const short8 ones = {0x3F80, 0x3F80, 0x3F80, 0x3F80, 0x3F80, 0x3F80, 0x3F80, 0x3F80};

  float4v o[4];
  float4v lf = (float4v){0.f, 0.f, 0.f, 0.f};
#pragma unroll
  for (int i = 0; i < 4; ++i) o[i] = (float4v){0.f, 0.f, 0.f, 0.f};

  for (int s0 = 0; s0 < 2048; s0 += 64) {
    __syncthreads();
    gload16(Kg + (size_t)s0 * 1024, lKd);
    gload16(Vg + s0, lVd);
    asm volatile("s_waitcnt vmcnt(0)" ::: "memory");
    __syncthreads();

    float4v sb[4];
#pragma unroll
    for (int i = 0; i < 4; ++i) {
      short8 k0 = *(const short8*)&lK[i * 1024 + fr0];
      short8 k1 = *(const short8*)&lK[i * 1024 + fr1];
      float4v c = (float4v){0.f, 0.f, 0.f, 0.f};
      c = MFMA16(qa0, k0, c);
      c = MFMA16(qa1, k1, c);
      sb[i] = c;
    }
#pragma unroll
    for (int i = 0; i < 4; ++i)
#pragma unroll
      for (int r = 0; r < 4; ++r)
        pl[(quad * 4 + r) * 68 + i * 16 + lane15] =
            f2bf_trunc(__builtin_amdgcn_exp2f(sb[i][r]));
    short4v p0a = *(const short4v*)&pl[lane15 * 68 + quad * 8];
    short4v p0b = *(const short4v*)&pl[lane15 * 68 + quad * 8 + 4];
    short4v p1a = *(const short4v*)&pl[lane15 * 68 + 32 + quad * 8];
    short4v p1b = *(const short4v*)&pl[lane15 * 68 + 32 + quad * 8 + 4];
    short8 pa0 = __builtin_shufflevector(p0a, p0b, 0, 1, 2, 3, 4, 5, 6, 7);
    short8 pa1 = __builtin_shufflevector(p1a, p1b, 0, 1, 2, 3, 4, 5, 6, 7);
    lf = MFMA16(pa0, ones, lf);
    lf = MFMA16(pa1, ones, lf);
#pragma unroll
    for (int nf = 0; nf < 4; ++nf) {
      short8 v0 = *(const short8*)&lV[nf * 1024 + fr0];
      short8 v1 = *(const short8*)&lV[nf * 1024 + fr1];
      o[nf] = MFMA16(pa0, v0, o[nf]);
      o[nf] = MFMA16(pa1, v1, o[nf]);
    }
  }

  float inv[4];
#pragma unroll
  for (int r = 0; r < 4; ++r) inv[r] = (lf[r] > 0.f) ? 1.0f / lf[r] : 0.0f;
  ushort* crow = ctxout + ((size_t)bh * 2048 + q0) * 64;
#pragma unroll
  for (int nf = 0; nf < 4; ++nf)
#pragma unroll
    for (int r = 0; r < 4; ++r)
      crow[(size_t)(quad * 4 + r) * 64 + nf * 16 + lane15] = f2bf_rne(o[nf][r] * inv[r]);
}

// ---------------------------------------------------------------------------
extern "C" void kernel_launch(void* const* d_in, const int* in_sizes, int n_in,
                              void* d_out, int out_size, void* d_ws, size_t ws_size,
                              hipStream_t stream) {
  const float* Q = (const float*)d_in[0];
  const float* K = (const float*)d_in[1];
  const float* V = (const float*)d_in[2];
  const float* Wq = (const float*)d_in[3];
  const float* bq = (const float*)d_in[4];
  const float* Wk = (const float*)d_in[5];
  const float* bk = (const float*)d_in[6];
  const float* Wv = (const float*)d_in[7];
  const float* bv = (const float*)d_in[8];
  const float* Wo = (const float*)d_in[9];
  const float* bo = (const float*)d_in[10];
  float* out = (float*)d_out;
  ushort* ws = (ushort*)d_ws;

  if (ws_size >= (58ull << 20)) {
    // big path (58 MB, u16 units):
    // [Qh 4M][Kh 4M][Vt 4M][Bt 3M (X 4M aliases)][WoB 1M @16M][Qb 4M][Kb 4M][Vb 4M]
    ushort* Qh = ws;
    ushort* Kh = Qh + (4 << 20);
    ushort* Vt = Kh + (4 << 20);
    ushort* BtQ = Vt + (4 << 20);
    ushort* BtK = BtQ + (1 << 20);
    ushort* BtV = BtK + (1 << 20);
    ushort* X = BtQ;  // 4M; Bt dead after proj3
    ushort* WoB = ws + (16ull << 20);
    ushort* Qb = WoB + (1 << 20);
    ushort* Kb = Qb + (4 << 20);
    ushort* Vb = Kb + (4 << 20);

    prep_kernel<<<dim3(7424), 256, 0, stream>>>(Q, K, V, Wo, Wq, Wk, Wv, Qb, Kb, Vb,
                                                WoB, BtQ, BtK, BtV);
    proj3_kernel<<<dim3(8, 32, 3), 256, 0, stream>>>(Qb, Kb, Vb, BtQ, BtK, BtV, bq, bk,
                                                     bv, Qh, Kh, Vt);
    attn_kernel<<<dim3(32, 16), 512, 0, stream>>>(Qh, Kh, Vt, X);
    gemm_out_kernel<<<dim3(16, 32), 256, 0, stream>>>(X, WoB, bo, out);
  } else {
    // fallback (32 MB): f32 A/B staging in the GEMMs
    ushort* Qh = ws;
    ushort* Kh = Qh + (4 << 20);
    ushort* Vt = Kh + (4 << 20);
    ushort* R = Vt + (4 << 20);
    ushort* BtQ = R;
    ushort* BtK = R + (1 << 20);
    ushort* BtV = R + (2 << 20);
    ushort* X = R;

    repack_w_kernel<<<dim3(16, 16, 3), 256, 0, stream>>>(Wq, Wk, Wv, BtQ, BtK, BtV);
    proj3f_kernel<<<dim3(8, 32, 3), 256, 0, stream>>>(Q, K, V, BtQ, BtK, BtV, bq, bk, bv,
                                                      Qh, Kh, Vt);
    attn_kernel<<<dim3(32, 16), 512, 0, stream>>>(Qh, Kh, Vt, X);
    gemm_btf_kernel<<<dim3(8, 32), 256, 0, stream>>>(X, Wo, bo, out);
  }
}